// Round 14
// baseline (143.112 us; speedup 1.0000x reference)
//
#include <hip/hip_runtime.h>
#include <hip/hip_bf16.h>

#define B_    128
#define S_    1024
#define DIN   64
#define DH    256
#define DLAT  256
#define DOUT  128
#define NPIECES 20

typedef short bf16x8 __attribute__((ext_vector_type(8)));
typedef float f32x4  __attribute__((ext_vector_type(4)));
typedef unsigned short u16x2 __attribute__((ext_vector_type(2)));

// ---------- bf16 helpers ----------
__device__ __forceinline__ unsigned short f2b(float f) {
    union { float f; unsigned u; } a; a.f = f;
    unsigned r = a.u + 0x7fffu + ((a.u >> 16) & 1u);   // RNE
    return (unsigned short)(r >> 16);
}
__device__ __forceinline__ float b2f_u(unsigned u16bits) {
    union { unsigned u; float f; } a; a.u = u16bits << 16;
    return a.f;
}
// packed u16 max/min — compiler-visible (emits v_pk_max_u16/v_pk_min_u16; proven)
__device__ __forceinline__ unsigned pmaxu(unsigned a, unsigned b) {
    union { unsigned u; u16x2 v; } A, Bv, R;
    A.u = a; Bv.u = b;
    R.v = __builtin_elementwise_max(A.v, Bv.v);
    return R.u;
}
__device__ __forceinline__ unsigned pminu(unsigned a, unsigned b) {
    union { unsigned u; u16x2 v; } A, Bv, R;
    A.u = a; Bv.u = b;
    R.v = __builtin_elementwise_min(A.v, Bv.v);
    return R.u;
}
__device__ __forceinline__ unsigned ror16(unsigned x) { return (x >> 16) | (x << 16); }
__device__ __forceinline__ unsigned permb(unsigned a, unsigned b, unsigned s) {
    return __builtin_amdgcn_perm(a, b, s);
}
// bf16 bits -> monotone-sortable u16 keys, packed (proven bit-trick)
__device__ __forceinline__ unsigned keycvt(unsigned u) {
    unsigned sgn = (u >> 15) & 0x00010001u;
    return u ^ ((sgn * 0x7FFFu) | 0x80008000u);
}

__device__ __forceinline__ bf16x8 cvt8(float4 a, float4 b) {
    bf16x8 o;
    o[0] = (short)f2b(a.x); o[1] = (short)f2b(a.y); o[2] = (short)f2b(a.z); o[3] = (short)f2b(a.w);
    o[4] = (short)f2b(b.x); o[5] = (short)f2b(b.y); o[6] = (short)f2b(b.z); o[7] = (short)f2b(b.w);
    return o;
}

// ---------------- k_prep: mask-count + weight packing, one launch ----------------
__global__ __launch_bounds__(256) void k_prep(const int* __restrict__ mask,
                                              int* __restrict__ nv,
                                              const float* __restrict__ w1,
                                              short* __restrict__ w1pk,
                                              const float* __restrict__ w2,
                                              short* __restrict__ w2pk) {
    __shared__ int parts[4];
    const int blk = blockIdx.x, t = threadIdx.x;
    if (blk < B_) {
        int sum = 0;
        #pragma unroll
        for (int q = 0; q < S_ / 256; ++q) sum += mask[blk * S_ + q * 256 + t];
        #pragma unroll
        for (int off = 32; off > 0; off >>= 1) sum += __shfl_down(sum, off, 64);
        if ((t & 63) == 0) parts[t >> 6] = sum;
        __syncthreads();
        if (t == 0) nv[blk] = max(parts[0] + parts[1] + parts[2] + parts[3], 2);
    } else if (blk < B_ + 8) {
        int c = (blk - B_) * 256 + t;
        int l = c & 63, ks = (c >> 6) % 2, nt = (c >> 6) / 2;
        int col = nt * 16 + (l & 15);
        int k0 = ks * 32 + (l >> 4) * 8;
        bf16x8 o;
        #pragma unroll
        for (int j = 0; j < 8; ++j) o[j] = (short)f2b(w1[(size_t)(k0 + j) * DH + col]);
        *(bf16x8*)(w1pk + (size_t)c * 8) = o;
    } else {
        int c = (blk - B_ - 8) * 256 + t;
        int l = c & 63, ks = (c >> 6) % 8, nt = (c >> 6) / 8;
        int col = nt * 16 + (l & 15);
        int k0 = ks * 32 + (l >> 4) * 8;
        bf16x8 o;
        #pragma unroll
        for (int j = 0; j < 8; ++j) o[j] = (short)f2b(w2[(size_t)(k0 + j) * DLAT + col]);
        *(bf16x8*)(w2pk + (size_t)c * 8) = o;
    }
}

// ---------------- fused phi MLP with MFMA; writes feat^T [B][C][S] bf16 ----------------
__global__ __launch_bounds__(256) void k_phi_mfma(const float* __restrict__ x,
                                                  const short* __restrict__ w1pk,
                                                  const short* __restrict__ w2pk,
                                                  const float* __restrict__ b1,
                                                  const float* __restrict__ b2,
                                                  const int* __restrict__ nv,
                                                  unsigned short* __restrict__ feat) {
    const int b    = blockIdx.y;
    const int tile = blockIdx.x;
    const int s0   = tile * 64;
    if (s0 >= nv[b]) return;
    const int tid  = threadIdx.x;
    const int w    = tid >> 6;
    const int lane = tid & 63;
    const int c15  = lane & 15;
    const int q    = lane >> 4;

    __shared__ __align__(16) char lds[64 * 256 * 2];

    f32x4 acc1[4][4];
    #pragma unroll
    for (int mt = 0; mt < 4; ++mt)
        #pragma unroll
        for (int nt = 0; nt < 4; ++nt) acc1[mt][nt] = (f32x4)0.f;

    const float* xb = x + ((size_t)b * S_ + s0) * DIN;
    bf16x8 a1[4][2], bw[4][2];
    #pragma unroll
    for (int mt = 0; mt < 4; ++mt)
        #pragma unroll
        for (int ks = 0; ks < 2; ++ks) {
            const float* p = xb + (size_t)(mt * 16 + c15) * DIN + ks * 32 + q * 8;
            float4 v0 = *(const float4*)p;
            float4 v1 = *(const float4*)(p + 4);
            a1[mt][ks] = cvt8(v0, v1);
        }
    #pragma unroll
    for (int nt = 0; nt < 4; ++nt)
        #pragma unroll
        for (int ks = 0; ks < 2; ++ks)
            bw[nt][ks] = *(const bf16x8*)(w1pk + ((size_t)((w * 4 + nt) * 2 + ks) * 64 + lane) * 8);
    #pragma unroll
    for (int ks = 0; ks < 2; ++ks)
        #pragma unroll
        for (int mt = 0; mt < 4; ++mt)
            #pragma unroll
            for (int nt = 0; nt < 4; ++nt)
                acc1[mt][nt] = __builtin_amdgcn_mfma_f32_16x16x32_bf16(a1[mt][ks], bw[nt][ks], acc1[mt][nt], 0, 0, 0);

    #pragma unroll
    for (int nt = 0; nt < 4; ++nt) {
        int chan = (w * 4 + nt) * 16 + c15;
        float bias = b1[chan];
        #pragma unroll
        for (int mt = 0; mt < 4; ++mt)
            #pragma unroll
            for (int r = 0; r < 4; ++r) {
                int pos = mt * 16 + q * 4 + r;
                float hv = fmaxf(acc1[mt][nt][r] + bias, 0.f);
                int byte = pos * 512 + chan * 2;
                byte ^= (pos & 7) << 4;
                *(unsigned short*)(lds + byte) = f2b(hv);
            }
    }
    __syncthreads();

    f32x4 acc2[4][4];
    #pragma unroll
    for (int mt = 0; mt < 4; ++mt)
        #pragma unroll
        for (int nt = 0; nt < 4; ++nt) acc2[mt][nt] = (f32x4)0.f;

    for (int ks2 = 0; ks2 < 8; ++ks2) {
        bf16x8 af[4];
        #pragma unroll
        for (int mt = 0; mt < 4; ++mt) {
            int pos = mt * 16 + c15;
            int byte = pos * 512 + ks2 * 64 + q * 16;
            byte ^= (pos & 7) << 4;
            af[mt] = *(const bf16x8*)(lds + byte);
        }
        #pragma unroll
        for (int nt = 0; nt < 4; ++nt) {
            bf16x8 bf_ = *(const bf16x8*)(w2pk + ((size_t)((w * 4 + nt) * 8 + ks2) * 64 + lane) * 8);
            #pragma unroll
            for (int mt = 0; mt < 4; ++mt)
                acc2[mt][nt] = __builtin_amdgcn_mfma_f32_16x16x32_bf16(af[mt], bf_, acc2[mt][nt], 0, 0, 0);
        }
    }
    __syncthreads();

    #pragma unroll
    for (int nt = 0; nt < 4; ++nt) {
        int chan = (w * 4 + nt) * 16 + c15;
        float bias = b2[chan];
        #pragma unroll
        for (int mt = 0; mt < 4; ++mt) {
            unsigned u0 = (unsigned)f2b(acc2[mt][nt][0] + bias) | ((unsigned)f2b(acc2[mt][nt][1] + bias) << 16);
            unsigned u1 = (unsigned)f2b(acc2[mt][nt][2] + bias) | ((unsigned)f2b(acc2[mt][nt][3] + bias) << 16);
            int pos0 = mt * 16 + q * 4;
            int byte = chan * 128 + pos0 * 2;
            byte ^= (chan & 7) << 4;
            *(uint2*)(lds + byte) = uint2{u0, u1};
        }
    }
    __syncthreads();

    #pragma unroll
    for (int it = 0; it < 8; ++it) {
        int L = it * 256 + tid;
        int chan = L >> 3, chunk = L & 7;
        int byte = chan * 128 + chunk * 16;
        byte ^= (chan & 7) << 4;
        uint4 val = *(const uint4*)(lds + byte);
        *(uint4*)((char*)(feat + ((size_t)b * DLAT + chan) * S_ + s0) + chunk * 16) = val;
    }
}

// ================= FSPool: LOOP-BASED packed-u16 bitonic (small I-footprint) =================

template <int T0, int NREGS>
__device__ __forceinline__ void loadcvt4(const unsigned short* __restrict__ fp, int i0, int n,
                                         unsigned (&r)[NREGS]) {
    uint4 a = *(const uint4*)(fp + i0);
    r[T0 + 0] = a.x; r[T0 + 1] = a.y; r[T0 + 2] = a.z; r[T0 + 3] = a.w;
    #pragma unroll
    for (int t = 0; t < 4; ++t) {
        unsigned key = keycvt(r[T0 + t]);
        int e0 = i0 + 2 * t;
        unsigned keep = (e0 + 1 < n) ? 0xFFFFFFFFu : ((e0 < n) ? 0x0000FFFFu : 0u);
        r[T0 + t] = key & keep;
    }
}

// loop-based bitonic sort of a 512-element slab (4 regs at T0), stages up to kmax.
// kmax=512: full 512-sort (each aligned 512-run desc). kmax=128: each 128-run desc.
template <int T0, int NREGS>
__device__ __forceinline__ void sort512_loop(unsigned (&r)[NREGS], int lane, int kmax) {
    // ---- k=2 (compile-time masks) ----
    #pragma unroll
    for (int t = 0; t < 4; ++t) {
        unsigned v = r[T0 + t], sw = ror16(v);
        unsigned mx = pmaxu(v, sw), mn = pminu(v, sw);
        r[T0 + t] = ((t & 1) == 0) ? permb(mn, mx, 0x07060100u) : permb(mx, mn, 0x07060100u);
    }
    // ---- k=4: j=2 pairs (0,1)(2,3), then j=1 inpack ----
    {
        unsigned mx0 = pmaxu(r[T0 + 0], r[T0 + 1]), mn0 = pminu(r[T0 + 0], r[T0 + 1]);
        r[T0 + 0] = mx0; r[T0 + 1] = mn0;
        unsigned mx1 = pmaxu(r[T0 + 2], r[T0 + 3]), mn1 = pminu(r[T0 + 2], r[T0 + 3]);
        r[T0 + 2] = mn1; r[T0 + 3] = mx1;
    }
    #pragma unroll
    for (int t = 0; t < 4; ++t) {
        unsigned v = r[T0 + t], sw = ror16(v);
        unsigned mx = pmaxu(v, sw), mn = pminu(v, sw);
        r[T0 + t] = (t < 2) ? permb(mn, mx, 0x07060100u) : permb(mx, mn, 0x07060100u);
    }
    // ---- k = 8..kmax: runtime loop; direction bit is LANE-UNIFORM for k>=8 ----
    #pragma clang loop unroll(disable)
    for (int k = 8; k <= kmax; k <<= 1) {
        const bool dzk = (((lane << 3) & k) == 0);
        #pragma clang loop unroll(disable)
        for (int j = k >> 1; j >= 8; j >>= 1) {
            const int m = j >> 3;
            const bool sel = (dzk == ((lane & m) == 0));
            #pragma unroll
            for (int t = 0; t < 4; ++t) {
                unsigned p = (unsigned)__shfl_xor((int)r[T0 + t], m, 64);
                unsigned mx = pmaxu(r[T0 + t], p), mn = pminu(r[T0 + t], p);
                r[T0 + t] = sel ? mx : mn;
            }
        }
        // j=4: reg pairs (0,2),(1,3)
        #pragma unroll
        for (int t = 0; t < 2; ++t) {
            unsigned a = r[T0 + t], bb = r[T0 + t + 2];
            unsigned mx = pmaxu(a, bb), mn = pminu(a, bb);
            r[T0 + t]     = dzk ? mx : mn;
            r[T0 + t + 2] = dzk ? mn : mx;
        }
        // j=2: reg pairs (0,1),(2,3)
        #pragma unroll
        for (int t = 0; t < 4; t += 2) {
            unsigned a = r[T0 + t], bb = r[T0 + t + 1];
            unsigned mx = pmaxu(a, bb), mn = pminu(a, bb);
            r[T0 + t]     = dzk ? mx : mn;
            r[T0 + t + 1] = dzk ? mn : mx;
        }
        // j=1: in-pack
        #pragma unroll
        for (int t = 0; t < 4; ++t) {
            unsigned v = r[T0 + t], sw = ror16(v);
            unsigned mx = pmaxu(v, sw), mn = pminu(v, sw);
            unsigned de = permb(mn, mx, 0x07060100u);
            unsigned as = permb(mx, mn, 0x07060100u);
            r[T0 + t] = dzk ? de : as;
        }
    }
}

// loop-based dual descending-merge of two bitonic 512-sequences (r[0..3], r[4..7])
__device__ __forceinline__ void merge512_dual_loop(unsigned (&r)[8], int lane) {
    #pragma clang loop unroll(disable)
    for (int j = 256; j >= 8; j >>= 1) {
        const int m = j >> 3;
        const bool sel = ((lane & m) == 0);
        #pragma unroll
        for (int t = 0; t < 8; ++t) {
            unsigned p = (unsigned)__shfl_xor((int)r[t], m, 64);
            unsigned mx = pmaxu(r[t], p), mn = pminu(r[t], p);
            r[t] = sel ? mx : mn;
        }
    }
    // j=4, j=2: pure-descending reg pairs within each 4-reg group
    #pragma unroll
    for (int g = 0; g < 8; g += 4) {
        #pragma unroll
        for (int t = 0; t < 2; ++t) {
            unsigned a = r[g + t], bb = r[g + t + 2];
            r[g + t]     = pmaxu(a, bb);
            r[g + t + 2] = pminu(a, bb);
        }
        #pragma unroll
        for (int t = 0; t < 4; t += 2) {
            unsigned a = r[g + t], bb = r[g + t + 1];
            r[g + t]     = pmaxu(a, bb);
            r[g + t + 1] = pminu(a, bb);
        }
    }
    // j=1: in-pack descending
    #pragma unroll
    for (int t = 0; t < 8; ++t) {
        unsigned sw = ror16(r[t]);
        r[t] = permb(pminu(r[t], sw), pmaxu(r[t], sw), 0x07060100u);
    }
}

// weighted sum over 4 regs (8 sorted elements at ranks rankBase..rankBase+7)
template <bool FASTW, int T0, int NREGS>
__device__ __forceinline__ float wsum(const unsigned (&r)[NREGS], int rankBase, int n,
                                      float invd, const float* __restrict__ pw) {
    float acc = 0.f;
    float k0 = 0.f, k1 = 0.f, k2 = 0.f; int ib = 0;
    if (FASTW) {
        float rb = fminf((float)rankBase * invd, 1.0f);
        ib = (int)((float)NPIECES * rb);
        if (ib > NPIECES) ib = NPIECES;
        k0 = pw[ib]; k1 = pw[min(ib + 1, NPIECES)]; k2 = pw[min(ib + 2, NPIECES)];
    }
    #pragma unroll
    for (int t = 0; t < 4; ++t)
        #pragma unroll
        for (int h = 0; h < 2; ++h) {
            int i = rankBase + 2 * t + h;
            unsigned key = h ? (r[T0 + t] >> 16) : (r[T0 + t] & 0xFFFFu);
            unsigned tneg = ((key >> 15) & 1u) ^ 1u;
            unsigned u = key ^ (0x8000u | (tneg * 0x7FFFu));
            float v = (i < n) ? b2f_u(u) : 0.f;
            float ratio = fminf((float)i * invd, 1.0f);
            float pos = (float)NPIECES * ratio;
            int idx = (int)pos;
            float frac = pos - (float)idx;
            float L, R;
            if (FASTW) { L = (idx == ib) ? k0 : k1; R = (idx == ib) ? k1 : k2; }
            else       { L = pw[idx];  R = pw[min(idx + 1, NPIECES)]; }
            acc = fmaf(v, fmaf(frac, R - L, L), acc);
        }
    return acc;
}

// ---------------- FSPool kernel: one wave per (b,c), unified paths ----------------
__global__ __launch_bounds__(256) void k_fspool11(const unsigned short* __restrict__ feat,
                                                  const int* __restrict__ nv,
                                                  const float* __restrict__ pool_w,
                                                  float* __restrict__ pooled) {
    const int gw   = blockIdx.x * 4 + (threadIdx.x >> 6);
    const int lane = threadIdx.x & 63;
    const int b = gw >> 8, c = gw & 255;
    const int n = nv[b];
    const unsigned short* fp = feat + ((size_t)b * DLAT + c) * S_;
    const float* pw = pool_w + c * (NPIECES + 1);
    const float invd = 1.0f / (float)(n - 1);

    float res;
    if (n <= 512) {
        unsigned r[4];
        loadcvt4<0>(fp, lane * 8, n, r);
        sort512_loop<0>(r, lane, 512);
        res = (n >= 141) ? wsum<true, 0>(r, lane * 8, n, invd, pw)
                         : wsum<false, 0>(r, lane * 8, n, invd, pw);
    } else {
        unsigned r[8];
        loadcvt4<0>(fp, lane * 8, n, r);           // A: elements 0..511
        loadcvt4<4>(fp, 512 + lane * 8, n, r);     // B: elements 512..1023
        sort512_loop<0>(r, lane, 512);             // A desc
        sort512_loop<4>(r, lane, (n <= 640) ? 128 : 512);   // B desc (short when tail <=128)
        // half-cleaner: A[i] vs B[511-i]  (proven shfl form)
        unsigned pa[4], pb[4];
        #pragma unroll
        for (int t = 0; t < 4; ++t) pa[t] = ror16(__shfl_xor(r[7 - t], 63, 64));
        #pragma unroll
        for (int t = 0; t < 4; ++t) pb[t] = ror16(__shfl_xor(r[3 - t], 63, 64));
        #pragma unroll
        for (int t = 0; t < 4; ++t) r[t]     = pmaxu(r[t], pa[t]);
        #pragma unroll
        for (int t = 0; t < 4; ++t) r[4 + t] = pminu(r[4 + t], pb[t]);
        merge512_dual_loop(r, lane);
        res = wsum<true, 0>(r, lane * 8, n, invd, pw)
            + wsum<true, 4>(r, 512 + lane * 8, n, invd, pw);
    }
    // proven shfl butterfly reduce
    #pragma unroll
    for (int off = 32; off > 0; off >>= 1) res += __shfl_xor(res, off, 64);
    if (lane == 0) pooled[gw] = res;
}

// ---------------- rho MLP ----------------
__global__ __launch_bounds__(256) void k_rho(const float* __restrict__ pooled,
                                             const float* __restrict__ w1,
                                             const float* __restrict__ b1,
                                             const float* __restrict__ w2,
                                             const float* __restrict__ b2,
                                             float* __restrict__ out) {
    const int b = blockIdx.x, t = threadIdx.x;
    __shared__ float pl[DLAT];
    __shared__ float h2[DH];
    pl[t] = pooled[b * DLAT + t];
    __syncthreads();
    float acc = b1[t];
    for (int k = 0; k < DLAT; ++k) acc = fmaf(pl[k], w1[k * DH + t], acc);
    h2[t] = fmaxf(acc, 0.f);
    __syncthreads();
    if (t < DOUT) {
        float o = b2[t];
        for (int k = 0; k < DH; ++k) o = fmaf(h2[k], w2[k * DOUT + t], o);
        out[b * DOUT + t] = o;
    }
}

extern "C" void kernel_launch(void* const* d_in, const int* in_sizes, int n_in,
                              void* d_out, int out_size, void* d_ws, size_t ws_size,
                              hipStream_t stream) {
    const float* x     = (const float*)d_in[0];
    const int*   mask  = (const int*)d_in[1];
    const float* pw1   = (const float*)d_in[2];
    const float* pb1   = (const float*)d_in[3];
    const float* pw2   = (const float*)d_in[4];
    const float* pb2   = (const float*)d_in[5];
    const float* rw1   = (const float*)d_in[6];
    const float* rb1   = (const float*)d_in[7];
    const float* rw2   = (const float*)d_in[8];
    const float* rb2   = (const float*)d_in[9];
    const float* poolw = (const float*)d_in[10];
    float* out = (float*)d_out;

    char* ws = (char*)d_ws;
    size_t off = 0;
    int* nv = (int*)ws;                          off += 1024;
    short* w1pk  = (short*)(ws + off);           off += (size_t)DIN * DH * 2;
    short* w2pk  = (short*)(ws + off);           off += (size_t)DH * DLAT * 2;
    unsigned short* feat = (unsigned short*)(ws + off); off += (size_t)B_ * DLAT * S_ * 2;
    float* pooled = (float*)(ws + off);

    k_prep<<<B_ + 8 + 32, 256, 0, stream>>>(mask, nv, pw1, w1pk, pw2, w2pk);
    k_phi_mfma<<<dim3(S_ / 64, B_), 256, 0, stream>>>(x, w1pk, w2pk, pb1, pb2, nv, feat);
    k_fspool11<<<(B_ * DLAT) / 4, 256, 0, stream>>>(feat, nv, poolw, pooled);
    k_rho<<<B_, 256, 0, stream>>>(pooled, rw1, rb1, rw2, rb2, out);
}

// Round 15
// 133.003 us; speedup vs baseline: 1.0760x; 1.0760x over previous
//
#include <hip/hip_runtime.h>
#include <hip/hip_bf16.h>

#define B_    128
#define S_    1024
#define DIN   64
#define DH    256
#define DLAT  256
#define DOUT  128
#define NPIECES 20

typedef short bf16x8 __attribute__((ext_vector_type(8)));
typedef float f32x4  __attribute__((ext_vector_type(4)));
typedef unsigned short u16x2 __attribute__((ext_vector_type(2)));

// ---------- bf16 helpers ----------
__device__ __forceinline__ unsigned short f2b(float f) {
    union { float f; unsigned u; } a; a.f = f;
    unsigned r = a.u + 0x7fffu + ((a.u >> 16) & 1u);   // RNE
    return (unsigned short)(r >> 16);
}
__device__ __forceinline__ float b2f_u(unsigned u16bits) {
    union { unsigned u; float f; } a; a.u = u16bits << 16;
    return a.f;
}
__device__ __forceinline__ unsigned pmaxu(unsigned a, unsigned b) {
    union { unsigned u; u16x2 v; } A, Bv, R;
    A.u = a; Bv.u = b;
    R.v = __builtin_elementwise_max(A.v, Bv.v);
    return R.u;
}
__device__ __forceinline__ unsigned pminu(unsigned a, unsigned b) {
    union { unsigned u; u16x2 v; } A, Bv, R;
    A.u = a; Bv.u = b;
    R.v = __builtin_elementwise_min(A.v, Bv.v);
    return R.u;
}
__device__ __forceinline__ unsigned ror16(unsigned x) { return (x >> 16) | (x << 16); }

__device__ __forceinline__ bf16x8 cvt8(float4 a, float4 b) {
    bf16x8 o;
    o[0] = (short)f2b(a.x); o[1] = (short)f2b(a.y); o[2] = (short)f2b(a.z); o[3] = (short)f2b(a.w);
    o[4] = (short)f2b(b.x); o[5] = (short)f2b(b.y); o[6] = (short)f2b(b.z); o[7] = (short)f2b(b.w);
    return o;
}

// ---------------- k_prep: mask-count + weight packing, one launch ----------------
__global__ __launch_bounds__(256) void k_prep(const int* __restrict__ mask,
                                              int* __restrict__ nv,
                                              const float* __restrict__ w1,
                                              short* __restrict__ w1pk,
                                              const float* __restrict__ w2,
                                              short* __restrict__ w2pk) {
    __shared__ int parts[4];
    const int blk = blockIdx.x, t = threadIdx.x;
    if (blk < B_) {
        int sum = 0;
        #pragma unroll
        for (int q = 0; q < S_ / 256; ++q) sum += mask[blk * S_ + q * 256 + t];
        #pragma unroll
        for (int off = 32; off > 0; off >>= 1) sum += __shfl_down(sum, off, 64);
        if ((t & 63) == 0) parts[t >> 6] = sum;
        __syncthreads();
        if (t == 0) nv[blk] = max(parts[0] + parts[1] + parts[2] + parts[3], 2);
    } else if (blk < B_ + 8) {
        int c = (blk - B_) * 256 + t;            // 2048 chunks, KT=2, N=DH
        int l = c & 63, ks = (c >> 6) % 2, nt = (c >> 6) / 2;
        int col = nt * 16 + (l & 15);
        int k0 = ks * 32 + (l >> 4) * 8;
        bf16x8 o;
        #pragma unroll
        for (int j = 0; j < 8; ++j) o[j] = (short)f2b(w1[(size_t)(k0 + j) * DH + col]);
        *(bf16x8*)(w1pk + (size_t)c * 8) = o;
    } else {
        int c = (blk - B_ - 8) * 256 + t;        // 8192 chunks, KT=8, N=DLAT
        int l = c & 63, ks = (c >> 6) % 8, nt = (c >> 6) / 8;
        int col = nt * 16 + (l & 15);
        int k0 = ks * 32 + (l >> 4) * 8;
        bf16x8 o;
        #pragma unroll
        for (int j = 0; j < 8; ++j) o[j] = (short)f2b(w2[(size_t)(k0 + j) * DLAT + col]);
        *(bf16x8*)(w2pk + (size_t)c * 8) = o;
    }
}

// ---------------- fused phi MLP with MFMA; direct f32 x loads; writes feat^T bf16 ----------------
__global__ __launch_bounds__(256) void k_phi_mfma(const float* __restrict__ x,
                                                  const short* __restrict__ w1pk,
                                                  const short* __restrict__ w2pk,
                                                  const float* __restrict__ b1,
                                                  const float* __restrict__ b2,
                                                  const int* __restrict__ nv,
                                                  unsigned short* __restrict__ feat) {
    const int b    = blockIdx.y;
    const int tile = blockIdx.x;          // 64-position tile
    const int s0   = tile * 64;
    if (s0 >= nv[b]) return;
    const int tid  = threadIdx.x;
    const int w    = tid >> 6;
    const int lane = tid & 63;
    const int c15  = lane & 15;
    const int q    = lane >> 4;

    __shared__ __align__(16) char lds[64 * 256 * 2];   // 32 KB

    // ---- layer 1: h = relu(x @ w1 + b1), M=64 K=64 N=256 ----
    f32x4 acc1[4][4];
    #pragma unroll
    for (int mt = 0; mt < 4; ++mt)
        #pragma unroll
        for (int nt = 0; nt < 4; ++nt) acc1[mt][nt] = (f32x4)0.f;

    const float* xb = x + ((size_t)b * S_ + s0) * DIN;
    bf16x8 a1[4][2], bw[4][2];
    #pragma unroll
    for (int mt = 0; mt < 4; ++mt)
        #pragma unroll
        for (int ks = 0; ks < 2; ++ks) {
            const float* p = xb + (size_t)(mt * 16 + c15) * DIN + ks * 32 + q * 8;
            float4 v0 = *(const float4*)p;
            float4 v1 = *(const float4*)(p + 4);
            a1[mt][ks] = cvt8(v0, v1);
        }
    #pragma unroll
    for (int nt = 0; nt < 4; ++nt)
        #pragma unroll
        for (int ks = 0; ks < 2; ++ks)
            bw[nt][ks] = *(const bf16x8*)(w1pk + ((size_t)((w * 4 + nt) * 2 + ks) * 64 + lane) * 8);
    #pragma unroll
    for (int ks = 0; ks < 2; ++ks)
        #pragma unroll
        for (int mt = 0; mt < 4; ++mt)
            #pragma unroll
            for (int nt = 0; nt < 4; ++nt)
                acc1[mt][nt] = __builtin_amdgcn_mfma_f32_16x16x32_bf16(a1[mt][ks], bw[nt][ks], acc1[mt][nt], 0, 0, 0);

    // relu + bias -> LDS h[pos][chan] bf16, swizzle byte ^= (pos&7)<<4
    #pragma unroll
    for (int nt = 0; nt < 4; ++nt) {
        int chan = (w * 4 + nt) * 16 + c15;
        float bias = b1[chan];
        #pragma unroll
        for (int mt = 0; mt < 4; ++mt)
            #pragma unroll
            for (int r = 0; r < 4; ++r) {
                int pos = mt * 16 + q * 4 + r;
                float hv = fmaxf(acc1[mt][nt][r] + bias, 0.f);
                int byte = pos * 512 + chan * 2;
                byte ^= (pos & 7) << 4;
                *(unsigned short*)(lds + byte) = f2b(hv);
            }
    }
    __syncthreads();

    // ---- layer 2: feat = h @ w2 + b2, M=64 K=256 N=256 ----
    f32x4 acc2[4][4];
    #pragma unroll
    for (int mt = 0; mt < 4; ++mt)
        #pragma unroll
        for (int nt = 0; nt < 4; ++nt) acc2[mt][nt] = (f32x4)0.f;

    for (int ks2 = 0; ks2 < 8; ++ks2) {
        bf16x8 af[4];
        #pragma unroll
        for (int mt = 0; mt < 4; ++mt) {
            int pos = mt * 16 + c15;
            int byte = pos * 512 + ks2 * 64 + q * 16;
            byte ^= (pos & 7) << 4;
            af[mt] = *(const bf16x8*)(lds + byte);
        }
        #pragma unroll
        for (int nt = 0; nt < 4; ++nt) {
            bf16x8 bf_ = *(const bf16x8*)(w2pk + ((size_t)((w * 4 + nt) * 8 + ks2) * 64 + lane) * 8);
            #pragma unroll
            for (int mt = 0; mt < 4; ++mt)
                acc2[mt][nt] = __builtin_amdgcn_mfma_f32_16x16x32_bf16(af[mt], bf_, acc2[mt][nt], 0, 0, 0);
        }
    }
    __syncthreads();   // reuse lds as feat^T tile [chan][pos]

    #pragma unroll
    for (int nt = 0; nt < 4; ++nt) {
        int chan = (w * 4 + nt) * 16 + c15;
        float bias = b2[chan];
        #pragma unroll
        for (int mt = 0; mt < 4; ++mt) {
            unsigned u0 = (unsigned)f2b(acc2[mt][nt][0] + bias) | ((unsigned)f2b(acc2[mt][nt][1] + bias) << 16);
            unsigned u1 = (unsigned)f2b(acc2[mt][nt][2] + bias) | ((unsigned)f2b(acc2[mt][nt][3] + bias) << 16);
            int pos0 = mt * 16 + q * 4;
            int byte = chan * 128 + pos0 * 2;
            byte ^= (chan & 7) << 4;
            *(uint2*)(lds + byte) = uint2{u0, u1};
        }
    }
    __syncthreads();

    #pragma unroll
    for (int it = 0; it < 8; ++it) {
        int L = it * 256 + tid;
        int chan = L >> 3, chunk = L & 7;
        int byte = chan * 128 + chunk * 16;
        byte ^= (chan & 7) << 4;
        uint4 val = *(const uint4*)(lds + byte);
        *(uint4*)((char*)(feat + ((size_t)b * DLAT + chan) * S_ + s0) + chunk * 16) = val;
    }
}

// ================= FSPool building blocks =================

// bf16 bits -> monotone-sortable u16 keys, packed
__device__ __forceinline__ unsigned keycvt(unsigned u) {
    unsigned sgn = (u >> 15) & 0x00010001u;
    return u ^ ((sgn * 0x7FFFu) | 0x80008000u);
}

// load 8 contiguous bf16 at element index i0, convert to sortable u16 keys, mask i>=n to 0
template <int T0, int NREGS>
__device__ __forceinline__ void loadcvt4(const unsigned short* __restrict__ fp, int i0, int n,
                                         unsigned (&r)[NREGS]) {
    uint4 a = *(const uint4*)(fp + i0);
    r[T0 + 0] = a.x; r[T0 + 1] = a.y; r[T0 + 2] = a.z; r[T0 + 3] = a.w;
    #pragma unroll
    for (int t = 0; t < 4; ++t) {
        unsigned key = keycvt(r[T0 + t]);
        int e0 = i0 + 2 * t;
        unsigned keep = (e0 + 1 < n) ? 0xFFFFFFFFu : ((e0 < n) ? 0x0000FFFFu : 0u);
        r[T0 + t] = key & keep;
    }
}

// one cross-lane compare-exchange pass (j = m*8), local idx = lane*8 + slot
template <int T0, int NREGS>
__device__ __forceinline__ void pass_cross(unsigned (&r)[NREGS], int lane, int m, int k) {
    bool lower = ((lane & m) == 0);
    bool dz = (((lane << 3) & k) == 0);
    bool sel = (dz == lower);
    #pragma unroll
    for (int t = 0; t < 4; ++t) {
        unsigned p = __shfl_xor(r[T0 + t], m, 64);
        unsigned mx = pmaxu(r[T0 + t], p), mn = pminu(r[T0 + t], p);
        r[T0 + t] = sel ? mx : mn;
    }
}

template <int T0, int NREGS>
__device__ __forceinline__ void pass_pair(unsigned (&r)[NREGS], int lane, int jr, int k) {
    #pragma unroll
    for (int t = 0; t < 4; ++t)
        if ((t & jr) == 0) {
            int ta = T0 + t, tb = T0 + (t | jr);
            unsigned mx = pmaxu(r[ta], r[tb]), mn = pminu(r[ta], r[tb]);
            bool dz = ((((lane << 3) | (t << 1)) & k) == 0);
            r[ta] = dz ? mx : mn;
            r[tb] = dz ? mn : mx;
        }
}

template <int T0, int NREGS>
__device__ __forceinline__ void pass_inpack(unsigned (&r)[NREGS], int lane, int k) {
    #pragma unroll
    for (int t = 0; t < 4; ++t) {
        unsigned v = r[T0 + t];
        unsigned sw = ror16(v);
        unsigned mx = pmaxu(v, sw), mn = pminu(v, sw);
        bool dz = ((((lane << 3) | (t << 1)) & k) == 0);
        unsigned de = (mx & 0x0000FFFFu) | (mn & 0xFFFF0000u);
        unsigned as = (mn & 0x0000FFFFu) | (mx & 0xFFFF0000u);
        r[T0 + t] = dz ? de : as;
    }
}

// full bitonic sort (descending) of NET elements laid out lane*8+slot on regs r[T0..T0+3]
template <int NET, int T0, int NREGS>
__device__ __forceinline__ void sort_net(unsigned (&r)[NREGS], int lane) {
    #pragma unroll
    for (int k = 2; k <= NET; k <<= 1) {
        #pragma unroll
        for (int j = k >> 1; j > 0; j >>= 1) {
            if (j >= 8)      pass_cross<T0>(r, lane, j >> 3, k);
            else if (j >= 2) pass_pair<T0>(r, lane, j >> 1, k);
            else             pass_inpack<T0>(r, lane, k);
        }
    }
}

// merge two bitonic 512-sequences (r[0..3] and r[4..7]) each to descending
__device__ __forceinline__ void merge_desc512_dual(unsigned (&r)[8], int lane) {
    #pragma unroll
    for (int j = 256; j >= 8; j >>= 1) {
        const int m = j >> 3;
        bool sel = ((lane & m) == 0);
        #pragma unroll
        for (int t = 0; t < 8; ++t) {
            unsigned p = __shfl_xor(r[t], m, 64);
            unsigned mx = pmaxu(r[t], p), mn = pminu(r[t], p);
            r[t] = sel ? mx : mn;
        }
    }
    #pragma unroll
    for (int jr = 2; jr >= 1; jr >>= 1)
        #pragma unroll
        for (int g = 0; g < 8; g += 4)
            #pragma unroll
            for (int t = 0; t < 4; ++t)
                if ((t & jr) == 0) {
                    unsigned a = r[g + t], bb = r[g + (t | jr)];
                    r[g + t]        = pmaxu(a, bb);
                    r[g + (t | jr)] = pminu(a, bb);
                }
    #pragma unroll
    for (int t = 0; t < 8; ++t) {
        unsigned sw = ror16(r[t]);
        unsigned mx = pmaxu(r[t], sw), mn = pminu(r[t], sw);
        r[t] = (mx & 0x0000FFFFu) | (mn & 0xFFFF0000u);
    }
}

// weighted sum over 4 regs (8 sorted elements at ranks rankBase..rankBase+7)
template <bool FASTW, int T0, int NREGS>
__device__ __forceinline__ float wsum(const unsigned (&r)[NREGS], int rankBase, int n,
                                      float invd, const float* __restrict__ pw) {
    float acc = 0.f;
    float k0 = 0.f, k1 = 0.f, k2 = 0.f; int ib = 0;
    if (FASTW) {
        float rb = fminf((float)rankBase * invd, 1.0f);
        ib = (int)((float)NPIECES * rb);
        if (ib > NPIECES) ib = NPIECES;
        k0 = pw[ib]; k1 = pw[min(ib + 1, NPIECES)]; k2 = pw[min(ib + 2, NPIECES)];
    }
    #pragma unroll
    for (int t = 0; t < 4; ++t)
        #pragma unroll
        for (int h = 0; h < 2; ++h) {
            int i = rankBase + 2 * t + h;
            unsigned key = h ? (r[T0 + t] >> 16) : (r[T0 + t] & 0xFFFFu);
            unsigned tneg = ((key >> 15) & 1u) ^ 1u;
            unsigned u = key ^ (0x8000u | (tneg * 0x7FFFu));
            float v = (i < n) ? b2f_u(u) : 0.f;
            float ratio = fminf((float)i * invd, 1.0f);
            float pos = (float)NPIECES * ratio;
            int idx = (int)pos;
            float frac = pos - (float)idx;
            float L, R;
            if (FASTW) { L = (idx == ib) ? k0 : k1; R = (idx == ib) ? k1 : k2; }
            else       { L = pw[idx];  R = pw[min(idx + 1, NPIECES)]; }
            acc = fmaf(v, fmaf(frac, R - L, L), acc);
        }
    return acc;
}

// fallback: full E=16 blocked bitonic (n > 640), returns per-lane partial
__device__ __forceinline__ float fsp_sum16(const unsigned short* __restrict__ fp,
                                           int n, const float* __restrict__ pw, int lane) {
    const int base = lane * 16;
    unsigned r[8];
    {
        const uint4* q4 = (const uint4*)(fp + base);
        uint4 a = q4[0], bq = q4[1];
        r[0] = a.x;  r[1] = a.y;  r[2] = a.z;  r[3] = a.w;
        r[4] = bq.x; r[5] = bq.y; r[6] = bq.z; r[7] = bq.w;
    }
    #pragma unroll
    for (int t = 0; t < 8; ++t) {
        unsigned key = keycvt(r[t]);
        int i0 = base + 2 * t;
        unsigned keep = (i0 + 1 < n) ? 0xFFFFFFFFu : ((i0 < n) ? 0x0000FFFFu : 0u);
        r[t] = key & keep;
    }
    #pragma unroll
    for (int k = 2; k <= 1024; k <<= 1) {
        #pragma unroll
        for (int j = k >> 1; j > 0; j >>= 1) {
            if (j >= 16) {
                const int m = j >> 4;
                const bool dz  = (((lane * 16) & k) == 0);
                const bool sel = (dz == ((lane & m) == 0));
                #pragma unroll
                for (int t = 0; t < 8; ++t) {
                    unsigned p = __shfl_xor(r[t], m, 64);
                    unsigned mx = pmaxu(r[t], p), mn = pminu(r[t], p);
                    r[t] = sel ? mx : mn;
                }
            } else if (j >= 2) {
                const int jr = j >> 1;
                #pragma unroll
                for (int t = 0; t < 8; ++t)
                    if ((t & jr) == 0) {
                        const int tb = t | jr;
                        unsigned mx = pmaxu(r[t], r[tb]), mn = pminu(r[t], r[tb]);
                        const bool dz = ((((lane * 16) | (2 * t)) & k) == 0);
                        r[t]  = dz ? mx : mn;
                        r[tb] = dz ? mn : mx;
                    }
            } else {
                #pragma unroll
                for (int t = 0; t < 8; ++t) {
                    unsigned sw = ror16(r[t]);
                    unsigned mx = pmaxu(r[t], sw), mn = pminu(r[t], sw);
                    const bool dz = ((((lane * 16) | (2 * t)) & k) == 0);
                    unsigned de = (mx & 0x0000FFFFu) | (mn & 0xFFFF0000u);
                    unsigned as = (mn & 0x0000FFFFu) | (mx & 0xFFFF0000u);
                    r[t] = dz ? de : as;
                }
            }
        }
    }
    const float invd = 1.0f / (float)(n - 1);
    float acc = 0.f;
    float rb = fminf((float)base * invd, 1.0f);
    int ib = (int)((float)NPIECES * rb);
    if (ib > NPIECES) ib = NPIECES;
    float k0 = pw[ib], k1 = pw[min(ib + 1, NPIECES)], k2 = pw[min(ib + 2, NPIECES)];
    #pragma unroll
    for (int t = 0; t < 8; ++t)
        #pragma unroll
        for (int h = 0; h < 2; ++h) {
            int i = base + 2 * t + h;
            unsigned key = h ? (r[t] >> 16) : (r[t] & 0xFFFFu);
            unsigned tneg = ((key >> 15) & 1u) ^ 1u;
            unsigned u = key ^ (0x8000u | (tneg * 0x7FFFu));
            float v = (i < n) ? b2f_u(u) : 0.f;
            float ratio = fminf((float)i * invd, 1.0f);
            float pos = (float)NPIECES * ratio;
            int idx = (int)pos;
            float frac = pos - (float)idx;
            float L = (idx == ib) ? k0 : k1, R = (idx == ib) ? k1 : k2;
            acc = fmaf(v, fmaf(frac, R - L, L), acc);
        }
    return acc;
}

// ---------------- FSPool kernel: one wave per (b,c) ----------------
__global__ __launch_bounds__(256) void k_fspool4(const unsigned short* __restrict__ feat,
                                                 const int* __restrict__ nv,
                                                 const float* __restrict__ pool_w,
                                                 float* __restrict__ pooled) {
    const int gw   = blockIdx.x * 4 + (threadIdx.x >> 6);
    const int lane = threadIdx.x & 63;
    const int b = gw >> 8, c = gw & 255;
    const int n = nv[b];
    const unsigned short* fp = feat + ((size_t)b * DLAT + c) * S_;
    const float* pw = pool_w + c * (NPIECES + 1);
    const float invd = 1.0f / (float)(n - 1);

    float res;
    if (n <= 512) {
        unsigned r[4];
        loadcvt4<0>(fp, lane * 8, n, r);
        sort_net<512, 0>(r, lane);
        res = (n >= 141) ? wsum<true, 0>(r, lane * 8, n, invd, pw)
                         : wsum<false, 0>(r, lane * 8, n, invd, pw);
    } else if (n <= 640) {
        unsigned r[8];
        loadcvt4<0>(fp, lane * 8, n, r);          // A: elements 0..511
        loadcvt4<4>(fp, 512 + lane * 8, n, r);    // B: elements 512..1023 (valid tail <=128)
        sort_net<512, 0>(r, lane);                // sort A desc
        sort_net<128, 4>(r, lane);                // sort B's 128-elem head desc (rest zero)
        // half-cleaner: A[i] vs B[511-i]  (lane^63, reg 7-t / 3-t, halves swapped)
        unsigned pa[4], pb[4];
        #pragma unroll
        for (int t = 0; t < 4; ++t) pa[t] = ror16(__shfl_xor(r[7 - t], 63, 64));
        #pragma unroll
        for (int t = 0; t < 4; ++t) pb[t] = ror16(__shfl_xor(r[3 - t], 63, 64));
        #pragma unroll
        for (int t = 0; t < 4; ++t) r[t]     = pmaxu(r[t], pa[t]);
        #pragma unroll
        for (int t = 0; t < 4; ++t) r[4 + t] = pminu(r[4 + t], pb[t]);
        merge_desc512_dual(r, lane);
        res = wsum<true, 0>(r, lane * 8, n, invd, pw)
            + wsum<true, 4>(r, 512 + lane * 8, n, invd, pw);
    } else {
        res = fsp_sum16(fp, n, pw, lane);
    }
    #pragma unroll
    for (int off = 32; off > 0; off >>= 1) res += __shfl_xor(res, off, 64);
    if (lane == 0) pooled[gw] = res;
}

// ---------------- rho MLP ----------------
__global__ __launch_bounds__(256) void k_rho(const float* __restrict__ pooled,
                                             const float* __restrict__ w1,
                                             const float* __restrict__ b1,
                                             const float* __restrict__ w2,
                                             const float* __restrict__ b2,
                                             float* __restrict__ out) {
    const int b = blockIdx.x, t = threadIdx.x;
    __shared__ float pl[DLAT];
    __shared__ float h2[DH];
    pl[t] = pooled[b * DLAT + t];
    __syncthreads();
    float acc = b1[t];
    for (int k = 0; k < DLAT; ++k) acc = fmaf(pl[k], w1[k * DH + t], acc);
    h2[t] = fmaxf(acc, 0.f);
    __syncthreads();
    if (t < DOUT) {
        float o = b2[t];
        for (int k = 0; k < DH; ++k) o = fmaf(h2[k], w2[k * DOUT + t], o);
        out[b * DOUT + t] = o;
    }
}

extern "C" void kernel_launch(void* const* d_in, const int* in_sizes, int n_in,
                              void* d_out, int out_size, void* d_ws, size_t ws_size,
                              hipStream_t stream) {
    const float* x     = (const float*)d_in[0];
    const int*   mask  = (const int*)d_in[1];
    const float* pw1   = (const float*)d_in[2];
    const float* pb1   = (const float*)d_in[3];
    const float* pw2   = (const float*)d_in[4];
    const float* pb2   = (const float*)d_in[5];
    const float* rw1   = (const float*)d_in[6];
    const float* rb1   = (const float*)d_in[7];
    const float* rw2   = (const float*)d_in[8];
    const float* rb2   = (const float*)d_in[9];
    const float* poolw = (const float*)d_in[10];
    float* out = (float*)d_out;

    char* ws = (char*)d_ws;
    size_t off = 0;
    int* nv = (int*)ws;                          off += 1024;
    short* w1pk  = (short*)(ws + off);           off += (size_t)DIN * DH * 2;
    short* w2pk  = (short*)(ws + off);           off += (size_t)DH * DLAT * 2;
    unsigned short* feat = (unsigned short*)(ws + off); off += (size_t)B_ * DLAT * S_ * 2;
    float* pooled = (float*)(ws + off);

    k_prep<<<B_ + 8 + 32, 256, 0, stream>>>(mask, nv, pw1, w1pk, pw2, w2pk);
    k_phi_mfma<<<dim3(S_ / 64, B_), 256, 0, stream>>>(x, w1pk, w2pk, pb1, pb2, nv, feat);
    k_fspool4<<<(B_ * DLAT) / 4, 256, 0, stream>>>(feat, nv, poolw, pooled);
    k_rho<<<B_, 256, 0, stream>>>(pooled, rw1, rb1, rw2, rb2, out);
}